// Round 1
// baseline (777.564 us; speedup 1.0000x reference)
//
#include <hip/hip_runtime.h>
#include <cstdint>

#define BB 2
#define NN 4096
#define MM 4096
#define KK 32
#define CC 64
#define R2C 0.0064f   // RADIUS^2 = 0.08^2

// ---------------------------------------------------------------------------
// Prep: pack (B,3,L) coords into float4 {x,y,z, x^2+y^2+z^2}, energy computed
// with the reference's reduction order ((x^2+y^2)+z^2) in strict fp32.
// ---------------------------------------------------------------------------
__global__ void prep_pts_kernel(const float* __restrict__ pts,
                                float4* __restrict__ out, int L) {
    int i = blockIdx.x * blockDim.x + threadIdx.x;
    if (i >= BB * L) return;
    int b = i / L, p = i - b * L;
    const float* base = pts + (size_t)b * 3 * L;
    float x = base[p], y = base[L + p], z = base[2 * L + p];
    float e = __fadd_rn(__fadd_rn(__fmul_rn(x, x), __fmul_rn(y, y)),
                        __fmul_rn(z, z));
    out[i] = make_float4(x, y, z, e);
}

// ---------------------------------------------------------------------------
// Transpose feat (B,C,M) -> featT (B,M,C) so per-neighbor gathers are
// contiguous 256B runs. 64x64 tiles, LDS padded to kill bank conflicts.
// ---------------------------------------------------------------------------
__global__ void transpose_feat_kernel(const float* __restrict__ feat,
                                      float* __restrict__ featT) {
    __shared__ float tile[64][65];
    int blk = blockIdx.x;
    int b = blk / (MM / 64);
    int m0 = (blk % (MM / 64)) * 64;
    int t = threadIdx.x;
    int mi = t & 63, cq = t >> 6;
    const float* src = feat + (size_t)b * CC * MM;
#pragma unroll
    for (int r = 0; r < 16; ++r) {
        int c = cq * 16 + r;
        tile[mi][c] = src[(size_t)c * MM + m0 + mi];
    }
    __syncthreads();
    int ci = t & 63, mq = t >> 6;
    float* dst = featT + ((size_t)b * MM + m0) * CC;
#pragma unroll
    for (int r = 0; r < 16; ++r) {
        int mm = mq * 16 + r;
        dst[(size_t)mm * CC + ci] = tile[mm][ci];
    }
}

// ---------------------------------------------------------------------------
// Selection: 1 wave per (b,n). Scan all M in chunks of 64, ballot the
// in-radius hits, stream-compact the first KK indices (ascending m — matches
// the reference top_k-of-masked-index exactly). Also row-min of clamped d2
// -> atomicAdd loss contribution (min over axis=2, mean).
// d2 arithmetic mirrors the reference: (pe+ke) - 2*fma_chain_cross, fp32.
// ---------------------------------------------------------------------------
__launch_bounds__(64)
__global__ void select_kernel(const float4* __restrict__ pointsT,
                              const float4* __restrict__ knnT,
                              int* __restrict__ idx_ws,
                              float* __restrict__ loss_ptr) {
    int lane = threadIdx.x;
    int blk = blockIdx.x;            // b*NN + n
    int b = blk / NN;
    float4 p4 = pointsT[blk];
    const float4* kb = knnT + (size_t)b * MM;
    __shared__ int sidx[KK];
    int cnt = 0;
    float minD = 1e30f;
    for (int c = 0; c < MM / 64; ++c) {
        int m = c * 64 + lane;
        float4 k4 = kb[m];
        float cross = __builtin_fmaf(p4.z, k4.z,
                      __builtin_fmaf(p4.y, k4.y, __fmul_rn(p4.x, k4.x)));
        float d2 = __fsub_rn(__fadd_rn(p4.w, k4.w), __fmul_rn(2.0f, cross));
        bool hit = d2 < R2C;
        minD = fminf(minD, fmaxf(d2, 0.0f));
        unsigned long long mask = __ballot(hit);
        if (hit) {
            int pos = cnt + __builtin_amdgcn_mbcnt_hi(
                              (unsigned)(mask >> 32),
                              __builtin_amdgcn_mbcnt_lo((unsigned)mask, 0));
            if (pos < KK) sidx[pos] = m;
        }
        cnt += __popcll(mask);
    }
    __syncthreads();
    if (lane < KK) {
        int fillv = (cnt > 0) ? sidx[0] : 0;   // no hits -> index 0 (ref semantics)
        int v = (lane < cnt) ? sidx[lane] : fillv;
        idx_ws[(size_t)blk * KK + lane] = v;
    }
    for (int off = 32; off > 0; off >>= 1)
        minD = fminf(minD, __shfl_xor(minD, off));
    if (lane == 0)
        atomicAdd(loss_ptr, sqrtf(1e-6f + minD) * (1.0f / (BB * NN)));
}

// ---------------------------------------------------------------------------
// Column min: 1 wave per (b,m), min over n -> loss (min over axis=1, mean).
// ---------------------------------------------------------------------------
__launch_bounds__(64)
__global__ void colmin_kernel(const float4* __restrict__ pointsT,
                              const float4* __restrict__ knnT,
                              float* __restrict__ loss_ptr) {
    int lane = threadIdx.x;
    int blk = blockIdx.x;            // b*MM + m
    int b = blk / MM;
    float4 k4 = knnT[blk];
    const float4* pb = pointsT + (size_t)b * NN;
    float minD = 1e30f;
    for (int c = 0; c < NN / 64; ++c) {
        float4 p4 = pb[c * 64 + lane];
        float cross = __builtin_fmaf(p4.z, k4.z,
                      __builtin_fmaf(p4.y, k4.y, __fmul_rn(p4.x, k4.x)));
        float d2 = __fsub_rn(__fadd_rn(p4.w, k4.w), __fmul_rn(2.0f, cross));
        minD = fminf(minD, fmaxf(d2, 0.0f));
    }
    for (int off = 32; off > 0; off >>= 1)
        minD = fminf(minD, __shfl_xor(minD, off));
    if (lane == 0)
        atomicAdd(loss_ptr, sqrtf(1e-6f + minD) * (1.0f / (BB * MM)));
}

// ---------------------------------------------------------------------------
// Fused MLP: 1 wave = 2 points; lane = (half, k). x[68] and h in registers,
// weights as wave-uniform scalar loads (s_load), chunked h1->h2 accumulation
// to keep VGPR ~180. agg = shuffle-reduce over the 32 k-lanes per half.
// ---------------------------------------------------------------------------
__launch_bounds__(64, 2)
__global__ void mlp_kernel(const float4* __restrict__ pointsT,
                           const float4* __restrict__ knnT,
                           const float* __restrict__ featT,
                           const int* __restrict__ idx_ws,
                           const float* __restrict__ w1, const float* __restrict__ b1,
                           const float* __restrict__ w2, const float* __restrict__ b2,
                           const float* __restrict__ w3, const float* __restrict__ b3,
                           float* __restrict__ out) {
    int lane = threadIdx.x;
    int half = lane >> 5, k = lane & 31;
    int pair = blockIdx.x;
    int b = pair / (NN / 2);
    int n = (pair - b * (NN / 2)) * 2 + half;
    int point = b * NN + n;
    float4 p4 = pointsT[point];
    int id = idx_ws[(size_t)point * KK + k];
    float4 nb = knnT[b * MM + id];

    float x[68];
    const float4* fb = (const float4*)(featT + ((size_t)(b * MM + id)) * CC);
#pragma unroll
    for (int c4 = 0; c4 < 16; ++c4) {
        float4 v = fb[c4];
        x[c4 * 4 + 0] = v.x; x[c4 * 4 + 1] = v.y;
        x[c4 * 4 + 2] = v.z; x[c4 * 4 + 3] = v.w;
    }
    float dx = nb.x - p4.x, dy = nb.y - p4.y, dz = nb.z - p4.z;
    x[64] = dx; x[65] = dy; x[66] = dz;
    x[67] = __fadd_rn(__fadd_rn(__fmul_rn(dx, dx), __fmul_rn(dy, dy)),
                      __fmul_rn(dz, dz));

    float h2[64];
#pragma unroll
    for (int o2 = 0; o2 < 64; ++o2) h2[o2] = b2[o2];

#pragma unroll 1
    for (int ch = 0; ch < 16; ++ch) {        // 16 chunks x 8 h1 outputs
        float h1v[8];
#pragma unroll
        for (int i = 0; i < 8; ++i) h1v[i] = b1[ch * 8 + i];
#pragma unroll
        for (int c = 0; c < 68; ++c) {
            float xv = x[c];
#pragma unroll
            for (int i = 0; i < 8; ++i)
                h1v[i] = fmaf(w1[(ch * 8 + i) * 68 + c], xv, h1v[i]);
        }
#pragma unroll
        for (int i = 0; i < 8; ++i) h1v[i] = fmaxf(h1v[i], 0.0f);
#pragma unroll
        for (int i = 0; i < 8; ++i) {
            float hv = h1v[i];
#pragma unroll
            for (int o2 = 0; o2 < 64; ++o2)
                h2[o2] = fmaf(w2[o2 * 128 + ch * 8 + i], hv, h2[o2]);
        }
    }
#pragma unroll
    for (int o2 = 0; o2 < 64; ++o2) h2[o2] = fmaxf(h2[o2], 0.0f);

    size_t outbase = ((size_t)b * 64) * NN + n;
#pragma unroll 1
    for (int g = 0; g < 16; ++g) {           // 4 h3 outputs at a time
        float acc[4];
#pragma unroll
        for (int i = 0; i < 4; ++i) acc[i] = b3[g * 4 + i];
#pragma unroll
        for (int o2 = 0; o2 < 64; ++o2) {
            float hv = h2[o2];
#pragma unroll
            for (int i = 0; i < 4; ++i)
                acc[i] = fmaf(w3[(g * 4 + i) * 64 + o2], hv, acc[i]);
        }
#pragma unroll
        for (int i = 0; i < 4; ++i) {
            float r = fmaxf(acc[i], 0.0f);
            r += __shfl_xor(r, 1);
            r += __shfl_xor(r, 2);
            r += __shfl_xor(r, 4);
            r += __shfl_xor(r, 8);
            r += __shfl_xor(r, 16);
            if (k == 0) out[outbase + (size_t)(g * 4 + i) * NN] = r;
        }
    }
}

// ---------------------------------------------------------------------------
extern "C" void kernel_launch(void* const* d_in, const int* in_sizes, int n_in,
                              void* d_out, int out_size, void* d_ws, size_t ws_size,
                              hipStream_t stream) {
    const float* points = (const float*)d_in[0];
    const float* knn    = (const float*)d_in[1];
    const float* feat   = (const float*)d_in[2];
    const float* w1 = (const float*)d_in[3];
    const float* b1 = (const float*)d_in[4];
    const float* w2 = (const float*)d_in[5];
    const float* b2 = (const float*)d_in[6];
    const float* w3 = (const float*)d_in[7];
    const float* b3 = (const float*)d_in[8];
    float* out = (float*)d_out;

    char* ws = (char*)d_ws;
    float4* pointsT = (float4*)ws;                 // 2*4096*16B = 128 KB
    float4* knnT    = (float4*)(ws + 131072);      // 128 KB
    float*  featT   = (float*)(ws + 262144);       // 2 MB
    int*    idx_ws  = (int*)(ws + 2359296);        // 1 MB

    float* loss_ptr = out + (size_t)BB * 64 * NN;  // last element of d_out
    hipMemsetAsync(loss_ptr, 0, sizeof(float), stream);

    prep_pts_kernel<<<(BB * NN + 255) / 256, 256, 0, stream>>>(points, pointsT, NN);
    prep_pts_kernel<<<(BB * MM + 255) / 256, 256, 0, stream>>>(knn, knnT, MM);
    transpose_feat_kernel<<<BB * (MM / 64), 256, 0, stream>>>(feat, featT);
    select_kernel<<<BB * NN, 64, 0, stream>>>(pointsT, knnT, idx_ws, loss_ptr);
    colmin_kernel<<<BB * MM, 64, 0, stream>>>(pointsT, knnT, loss_ptr);
    mlp_kernel<<<BB * NN / 2, 64, 0, stream>>>(pointsT, knnT, featT, idx_ws,
                                               w1, b1, w2, b2, w3, b3, out);
}

// Round 2
// 615.683 us; speedup vs baseline: 1.2629x; 1.2629x over previous
//
#include <hip/hip_runtime.h>
#include <cstdint>

#define BB 2
#define NN 4096
#define MM 4096
#define KK 32
#define CC 64
#define R2C 0.0064f   // RADIUS^2 = 0.08^2

typedef float v16f __attribute__((ext_vector_type(16)));
typedef float v8f  __attribute__((ext_vector_type(8)));

// ---------------------------------------------------------------------------
// Prep: pack (B,3,L) coords into float4 {x,y,z, x^2+y^2+z^2}, energy computed
// with the reference's reduction order ((x^2+y^2)+z^2) in strict fp32.
// ---------------------------------------------------------------------------
__global__ void prep_pts_kernel(const float* __restrict__ pts,
                                float4* __restrict__ out, int L) {
    int i = blockIdx.x * blockDim.x + threadIdx.x;
    if (i >= BB * L) return;
    int b = i / L, p = i - b * L;
    const float* base = pts + (size_t)b * 3 * L;
    float x = base[p], y = base[L + p], z = base[2 * L + p];
    float e = __fadd_rn(__fadd_rn(__fmul_rn(x, x), __fmul_rn(y, y)),
                        __fmul_rn(z, z));
    out[i] = make_float4(x, y, z, e);
}

// ---------------------------------------------------------------------------
// Pack weights into FMA-consumption order so the MLP's wave-uniform reads are
// contiguous s_load runs.
//   w1p[ch][c][i] = w1[(ch*8+i)*68 + c]          (16*68*8 = 8704)
//   w2p[i][o2]    = w2[o2*128 + i]               (128*64  = 8192)
//   w3p[g][o2][i] = w3[(g*4+i)*64 + o2]          (16*64*4 = 4096)
// ---------------------------------------------------------------------------
__global__ void pack_w_kernel(const float* __restrict__ w1,
                              const float* __restrict__ w2,
                              const float* __restrict__ w3,
                              float* __restrict__ w1p,
                              float* __restrict__ w2p,
                              float* __restrict__ w3p) {
    int t = blockIdx.x * blockDim.x + threadIdx.x;
    if (t < 8704) {
        int i = t & 7, c = (t >> 3) % 68, ch = t / (68 * 8);
        w1p[t] = w1[(ch * 8 + i) * 68 + c];
    }
    if (t < 8192) {
        w2p[t] = w2[(t & 63) * 128 + (t >> 6)];
    }
    if (t < 4096) {
        int g = t >> 8, r = t & 255, o2 = r >> 2, i = r & 3;
        w3p[t] = w3[(g * 4 + i) * 64 + o2];
    }
}

// ---------------------------------------------------------------------------
// Transpose feat (B,C,M) -> featT (B,M,C) so per-neighbor gathers are
// contiguous 256B runs.
// ---------------------------------------------------------------------------
__global__ void transpose_feat_kernel(const float* __restrict__ feat,
                                      float* __restrict__ featT) {
    __shared__ float tile[64][65];
    int blk = blockIdx.x;
    int b = blk / (MM / 64);
    int m0 = (blk % (MM / 64)) * 64;
    int t = threadIdx.x;
    int mi = t & 63, cq = t >> 6;
    const float* src = feat + (size_t)b * CC * MM;
#pragma unroll
    for (int r = 0; r < 16; ++r) {
        int c = cq * 16 + r;
        tile[mi][c] = src[(size_t)c * MM + m0 + mi];
    }
    __syncthreads();
    int ci = t & 63, mq = t >> 6;
    float* dst = featT + ((size_t)b * MM + m0) * CC;
#pragma unroll
    for (int r = 0; r < 16; ++r) {
        int mm = mq * 16 + r;
        dst[(size_t)mm * CC + ci] = tile[mm][ci];
    }
}

// ---------------------------------------------------------------------------
// Selection: 1 wave per (b,n). Ballot + stream-compact the first KK in-radius
// indices (ascending m == reference top_k-of-masked-index). Row-min -> loss.
// ---------------------------------------------------------------------------
__launch_bounds__(64)
__global__ void select_kernel(const float4* __restrict__ pointsT,
                              const float4* __restrict__ knnT,
                              int* __restrict__ idx_ws,
                              float* __restrict__ loss_ptr) {
    int lane = threadIdx.x;
    int blk = blockIdx.x;            // b*NN + n
    int b = blk / NN;
    float4 p4 = pointsT[blk];
    const float4* kb = knnT + (size_t)b * MM;
    __shared__ int sidx[KK];
    int cnt = 0;
    float minD = 1e30f;
    for (int c = 0; c < MM / 64; ++c) {
        int m = c * 64 + lane;
        float4 k4 = kb[m];
        float cross = __builtin_fmaf(p4.z, k4.z,
                      __builtin_fmaf(p4.y, k4.y, __fmul_rn(p4.x, k4.x)));
        float d2 = __fsub_rn(__fadd_rn(p4.w, k4.w), __fmul_rn(2.0f, cross));
        bool hit = d2 < R2C;
        minD = fminf(minD, fmaxf(d2, 0.0f));
        unsigned long long mask = __ballot(hit);
        if (hit) {
            int pos = cnt + __builtin_amdgcn_mbcnt_hi(
                              (unsigned)(mask >> 32),
                              __builtin_amdgcn_mbcnt_lo((unsigned)mask, 0));
            if (pos < KK) sidx[pos] = m;
        }
        cnt += __popcll(mask);
    }
    __syncthreads();
    if (lane < KK) {
        int fillv = (cnt > 0) ? sidx[0] : 0;
        int v = (lane < cnt) ? sidx[lane] : fillv;
        idx_ws[(size_t)blk * KK + lane] = v;
    }
    for (int off = 32; off > 0; off >>= 1)
        minD = fminf(minD, __shfl_xor(minD, off));
    if (lane == 0)
        atomicAdd(loss_ptr, sqrtf(1e-6f + minD) * (1.0f / (BB * NN)));
}

// ---------------------------------------------------------------------------
// Column min: 1 wave per (b,m), min over n -> loss.
// ---------------------------------------------------------------------------
__launch_bounds__(64)
__global__ void colmin_kernel(const float4* __restrict__ pointsT,
                              const float4* __restrict__ knnT,
                              float* __restrict__ loss_ptr) {
    int lane = threadIdx.x;
    int blk = blockIdx.x;            // b*MM + m
    int b = blk / MM;
    float4 k4 = knnT[blk];
    const float4* pb = pointsT + (size_t)b * NN;
    float minD = 1e30f;
    for (int c = 0; c < NN / 64; ++c) {
        float4 p4 = pb[c * 64 + lane];
        float cross = __builtin_fmaf(p4.z, k4.z,
                      __builtin_fmaf(p4.y, k4.y, __fmul_rn(p4.x, k4.x)));
        float d2 = __fsub_rn(__fadd_rn(p4.w, k4.w), __fmul_rn(2.0f, cross));
        minD = fminf(minD, fmaxf(d2, 0.0f));
    }
    for (int off = 32; off > 0; off >>= 1)
        minD = fminf(minD, __shfl_xor(minD, off));
    if (lane == 0)
        atomicAdd(loss_ptr, sqrtf(1e-6f + minD) * (1.0f / (BB * MM)));
}

// ---------------------------------------------------------------------------
// Fused MLP. 1 wave = 2 points; lane = (half, k). All live state in
// ext_vector_type SSA values -> guaranteed VGPR residency (R1's float arrays
// were demoted to scratch: VGPR_Count=80, VALUBusy=49%).
// ---------------------------------------------------------------------------
__device__ inline void l1_acc(v8f& h1, const float* __restrict__ wp,
                              const v16f& xv, int cb) {
#pragma unroll
    for (int cc = 0; cc < 16; ++cc) {
        float xs = xv[cc];
#pragma unroll
        for (int i = 0; i < 8; ++i)
            h1[i] = fmaf(wp[(cb + cc) * 8 + i], xs, h1[i]);
    }
}

__device__ inline void l2_acc(v16f& h2, const float* __restrict__ w2row,
                              float hv, int ob) {
#pragma unroll
    for (int o = 0; o < 16; ++o)
        h2[o] = fmaf(w2row[ob + o], hv, h2[o]);
}

__device__ inline void l3_acc(float* __restrict__ acc,
                              const float* __restrict__ wrow,
                              const v16f& h2, int o2b) {
#pragma unroll
    for (int o = 0; o < 16; ++o) {
        float hv = h2[o];
#pragma unroll
        for (int i = 0; i < 4; ++i)
            acc[i] = fmaf(wrow[(o2b + o) * 4 + i], hv, acc[i]);
    }
}

__device__ inline v16f load16(const float4* __restrict__ fb, int base4) {
    float4 a = fb[base4], b = fb[base4 + 1], c = fb[base4 + 2], d = fb[base4 + 3];
    return (v16f){a.x, a.y, a.z, a.w, b.x, b.y, b.z, b.w,
                  c.x, c.y, c.z, c.w, d.x, d.y, d.z, d.w};
}

__launch_bounds__(64)
__global__ void mlp_kernel(const float4* __restrict__ pointsT,
                           const float4* __restrict__ knnT,
                           const float* __restrict__ featT,
                           const int* __restrict__ idx_ws,
                           const float* __restrict__ w1p, const float* __restrict__ b1,
                           const float* __restrict__ w2p, const float* __restrict__ b2,
                           const float* __restrict__ w3p, const float* __restrict__ b3,
                           float* __restrict__ out) {
    int lane = threadIdx.x;
    int hh = lane >> 5, k = lane & 31;
    int pair = blockIdx.x;
    int b = pair / (NN / 2);
    int n = (pair - b * (NN / 2)) * 2 + hh;
    int point = b * NN + n;
    float4 p4 = pointsT[point];
    int id = idx_ws[(size_t)point * KK + k];
    float4 nb = knnT[b * MM + id];

    const float4* fb = (const float4*)(featT + ((size_t)(b * MM + id)) * CC);
    v16f x0 = load16(fb, 0), x1 = load16(fb, 4), x2 = load16(fb, 8), x3 = load16(fb, 12);
    float dx = nb.x - p4.x, dy = nb.y - p4.y, dz = nb.z - p4.z;
    float dd = __fadd_rn(__fadd_rn(__fmul_rn(dx, dx), __fmul_rn(dy, dy)),
                         __fmul_rn(dz, dz));

    v16f h2a, h2b, h2c, h2d;
#pragma unroll
    for (int o = 0; o < 16; ++o) {
        h2a[o] = b2[o]; h2b[o] = b2[16 + o];
        h2c[o] = b2[32 + o]; h2d[o] = b2[48 + o];
    }

#pragma unroll 1
    for (int ch = 0; ch < 16; ++ch) {
        v8f h1;
        const float* b1c = b1 + ch * 8;
#pragma unroll
        for (int i = 0; i < 8; ++i) h1[i] = b1c[i];
        const float* wp = w1p + ch * 68 * 8;
        l1_acc(h1, wp, x0, 0);
        l1_acc(h1, wp, x1, 16);
        l1_acc(h1, wp, x2, 32);
        l1_acc(h1, wp, x3, 48);
        // tail: dx, dy, dz, dist
#pragma unroll
        for (int i = 0; i < 8; ++i) {
            float v = h1[i];
            v = fmaf(wp[64 * 8 + i], dx, v);
            v = fmaf(wp[65 * 8 + i], dy, v);
            v = fmaf(wp[66 * 8 + i], dz, v);
            v = fmaf(wp[67 * 8 + i], dd, v);
            h1[i] = fmaxf(v, 0.0f);          // ReLU layer 1
        }
#pragma unroll
        for (int i = 0; i < 8; ++i) {
            float hv = h1[i];
            const float* w2row = w2p + (ch * 8 + i) * 64;
            l2_acc(h2a, w2row, hv, 0);
            l2_acc(h2b, w2row, hv, 16);
            l2_acc(h2c, w2row, hv, 32);
            l2_acc(h2d, w2row, hv, 48);
        }
    }
#pragma unroll
    for (int o = 0; o < 16; ++o) {
        h2a[o] = fmaxf(h2a[o], 0.0f); h2b[o] = fmaxf(h2b[o], 0.0f);
        h2c[o] = fmaxf(h2c[o], 0.0f); h2d[o] = fmaxf(h2d[o], 0.0f);
    }

    size_t outbase = ((size_t)b * 64) * NN + n;
#pragma unroll 1
    for (int g = 0; g < 16; ++g) {
        float acc[4];
#pragma unroll
        for (int i = 0; i < 4; ++i) acc[i] = b3[g * 4 + i];
        const float* wrow = w3p + g * 256;
        l3_acc(acc, wrow, h2a, 0);
        l3_acc(acc, wrow, h2b, 16);
        l3_acc(acc, wrow, h2c, 32);
        l3_acc(acc, wrow, h2d, 48);
#pragma unroll
        for (int i = 0; i < 4; ++i) {
            float r = fmaxf(acc[i], 0.0f);
            r += __shfl_xor(r, 1);
            r += __shfl_xor(r, 2);
            r += __shfl_xor(r, 4);
            r += __shfl_xor(r, 8);
            r += __shfl_xor(r, 16);
            if (k == 0) out[outbase + (size_t)(g * 4 + i) * NN] = r;
        }
    }
}

// ---------------------------------------------------------------------------
extern "C" void kernel_launch(void* const* d_in, const int* in_sizes, int n_in,
                              void* d_out, int out_size, void* d_ws, size_t ws_size,
                              hipStream_t stream) {
    const float* points = (const float*)d_in[0];
    const float* knn    = (const float*)d_in[1];
    const float* feat   = (const float*)d_in[2];
    const float* w1 = (const float*)d_in[3];
    const float* b1 = (const float*)d_in[4];
    const float* w2 = (const float*)d_in[5];
    const float* b2 = (const float*)d_in[6];
    const float* w3 = (const float*)d_in[7];
    const float* b3 = (const float*)d_in[8];
    float* out = (float*)d_out;

    char* ws = (char*)d_ws;
    float4* pointsT = (float4*)ws;                 // 128 KB
    float4* knnT    = (float4*)(ws + 131072);      // 128 KB
    float*  featT   = (float*)(ws + 262144);       // 2 MB
    int*    idx_ws  = (int*)(ws + 2359296);        // 1 MB
    float*  w1p     = (float*)(ws + 3407872);      // 34816 B
    float*  w2p     = (float*)(ws + 3442688);      // 32 KB
    float*  w3p     = (float*)(ws + 3475456);      // 16 KB

    float* loss_ptr = out + (size_t)BB * 64 * NN;  // last element of d_out
    hipMemsetAsync(loss_ptr, 0, sizeof(float), stream);

    prep_pts_kernel<<<(BB * NN + 255) / 256, 256, 0, stream>>>(points, pointsT, NN);
    prep_pts_kernel<<<(BB * MM + 255) / 256, 256, 0, stream>>>(knn, knnT, MM);
    pack_w_kernel<<<34, 256, 0, stream>>>(w1, w2, w3, w1p, w2p, w3p);
    transpose_feat_kernel<<<BB * (MM / 64), 256, 0, stream>>>(feat, featT);
    select_kernel<<<BB * NN, 64, 0, stream>>>(pointsT, knnT, idx_ws, loss_ptr);
    colmin_kernel<<<BB * MM, 64, 0, stream>>>(pointsT, knnT, loss_ptr);
    mlp_kernel<<<BB * NN / 2, 64, 0, stream>>>(pointsT, knnT, featT, idx_ws,
                                               w1p, b1, w2p, b2, w3p, b3, out);
}

// Round 3
// 156.415 us; speedup vs baseline: 4.9712x; 3.9362x over previous
//
#include <hip/hip_runtime.h>
#include <cstdint>

#define BB 2
#define NN 4096
#define MM 4096
#define KK 32
#define CC 64
#define R2C 0.0064f   // RADIUS^2

typedef _Float16 v8h __attribute__((ext_vector_type(8)));
typedef _Float16 v4h __attribute__((ext_vector_type(4)));
typedef float    v4f __attribute__((ext_vector_type(4)));

// ---------------------------------------------------------------------------
// Prep: pack (B,3,L) coords into float4 {x,y,z, x^2+y^2+z^2} (strict fp32,
// reference reduction order) — selection/loss math must stay exact fp32.
// ---------------------------------------------------------------------------
__global__ void prep_pts_kernel(const float* __restrict__ pts,
                                float4* __restrict__ out, int L) {
    int i = blockIdx.x * blockDim.x + threadIdx.x;
    if (i >= BB * L) return;
    int b = i / L, p = i - b * L;
    const float* base = pts + (size_t)b * 3 * L;
    float x = base[p], y = base[L + p], z = base[2 * L + p];
    float e = __fadd_rn(__fadd_rn(__fmul_rn(x, x), __fmul_rn(y, y)),
                        __fmul_rn(z, z));
    out[i] = make_float4(x, y, z, e);
}

// ---------------------------------------------------------------------------
// Pack weights to f16 in A-operand-friendly [m][k] row-major layouts.
//   w1h: [128][96]  (K padded 68 -> 96 with zeros)
//   w2h: [64][128]  (identity copy of w2)
//   w3h: [64][64]   (identity copy of w3)
// ---------------------------------------------------------------------------
__global__ void pack_w_kernel(const float* __restrict__ w1,
                              const float* __restrict__ w2,
                              const float* __restrict__ w3,
                              _Float16* __restrict__ w1h,
                              _Float16* __restrict__ w2h,
                              _Float16* __restrict__ w3h) {
    int t = blockIdx.x * blockDim.x + threadIdx.x;
    if (t < 128 * 96) {
        int r = t / 96, k = t - r * 96;
        w1h[t] = (_Float16)((k < 68) ? w1[r * 68 + k] : 0.0f);
    }
    if (t < 64 * 128) w2h[t] = (_Float16)w2[t];
    if (t < 64 * 64)  w3h[t] = (_Float16)w3[t];
}

// ---------------------------------------------------------------------------
// Transpose feat (B,C,M) -> featH (B,M,C) as f16 (contiguous 128B per point).
// ---------------------------------------------------------------------------
__global__ void transpose_feat_kernel(const float* __restrict__ feat,
                                      _Float16* __restrict__ featH) {
    __shared__ float tile[64][65];
    int blk = blockIdx.x;
    int b = blk / (MM / 64);
    int m0 = (blk % (MM / 64)) * 64;
    int t = threadIdx.x;
    int mi = t & 63, cq = t >> 6;
    const float* src = feat + (size_t)b * CC * MM;
#pragma unroll
    for (int r = 0; r < 16; ++r) {
        int c = cq * 16 + r;
        tile[mi][c] = src[(size_t)c * MM + m0 + mi];
    }
    __syncthreads();
    int ci = t & 63, mq = t >> 6;
    _Float16* dst = featH + ((size_t)b * MM + m0) * CC;
#pragma unroll
    for (int r = 0; r < 16; ++r) {
        int mm = mq * 16 + r;
        dst[(size_t)mm * CC + ci] = (_Float16)tile[mm][ci];
    }
}

// ---------------------------------------------------------------------------
// Selection: 1 wave per (b,n). Ballot + stream-compact first KK in-radius
// indices (ascending m == reference top_k-of-masked-index). Row-min -> loss
// partial (spread atomics: 1024 slots x 32B stride).
// ---------------------------------------------------------------------------
__launch_bounds__(64)
__global__ void select_kernel(const float4* __restrict__ pointsT,
                              const float4* __restrict__ knnT,
                              int* __restrict__ idx_ws,
                              float* __restrict__ lossbuf) {
    int lane = threadIdx.x;
    int blk = blockIdx.x;            // b*NN + n
    int b = blk / NN;
    float4 p4 = pointsT[blk];
    const float4* kb = knnT + (size_t)b * MM;
    __shared__ int sidx[KK];
    int cnt = 0;
    float minD = 1e30f;
    for (int c = 0; c < MM / 64; ++c) {
        int m = c * 64 + lane;
        float4 k4 = kb[m];
        float cross = __builtin_fmaf(p4.z, k4.z,
                      __builtin_fmaf(p4.y, k4.y, __fmul_rn(p4.x, k4.x)));
        float d2 = __fsub_rn(__fadd_rn(p4.w, k4.w), __fmul_rn(2.0f, cross));
        bool hit = d2 < R2C;
        minD = fminf(minD, fmaxf(d2, 0.0f));
        unsigned long long mask = __ballot(hit);
        if (hit) {
            int pos = cnt + __builtin_amdgcn_mbcnt_hi(
                              (unsigned)(mask >> 32),
                              __builtin_amdgcn_mbcnt_lo((unsigned)mask, 0));
            if (pos < KK) sidx[pos] = m;
        }
        cnt += __popcll(mask);
    }
    __syncthreads();
    if (lane < KK) {
        int fillv = (cnt > 0) ? sidx[0] : 0;
        int v = (lane < cnt) ? sidx[lane] : fillv;
        idx_ws[(size_t)blk * KK + lane] = v;
    }
    for (int off = 32; off > 0; off >>= 1)
        minD = fminf(minD, __shfl_xor(minD, off));
    if (lane == 0)
        atomicAdd(lossbuf + (blk & 1023) * 8,
                  sqrtf(1e-6f + minD) * (1.0f / (BB * NN)));
}

// ---------------------------------------------------------------------------
// Column min: 1 wave per (b,m), min over n -> loss partial.
// ---------------------------------------------------------------------------
__launch_bounds__(64)
__global__ void colmin_kernel(const float4* __restrict__ pointsT,
                              const float4* __restrict__ knnT,
                              float* __restrict__ lossbuf) {
    int lane = threadIdx.x;
    int blk = blockIdx.x;            // b*MM + m
    int b = blk / MM;
    float4 k4 = knnT[blk];
    const float4* pb = pointsT + (size_t)b * NN;
    float minD = 1e30f;
    for (int c = 0; c < NN / 64; ++c) {
        float4 p4 = pb[c * 64 + lane];
        float cross = __builtin_fmaf(p4.z, k4.z,
                      __builtin_fmaf(p4.y, k4.y, __fmul_rn(p4.x, k4.x)));
        float d2 = __fsub_rn(__fadd_rn(p4.w, k4.w), __fmul_rn(2.0f, cross));
        minD = fminf(minD, fmaxf(d2, 0.0f));
    }
    for (int off = 32; off > 0; off >>= 1)
        minD = fminf(minD, __shfl_xor(minD, off));
    if (lane == 0)
        atomicAdd(lossbuf + (blk & 1023) * 8,
                  sqrtf(1e-6f + minD) * (1.0f / (BB * MM)));
}

// ---------------------------------------------------------------------------
// Sum the 1024 loss partials -> out[loss].
// ---------------------------------------------------------------------------
__global__ void loss_reduce_kernel(const float* __restrict__ lossbuf,
                                   float* __restrict__ out_loss) {
    int t = threadIdx.x;             // 256 threads
    float s = lossbuf[t * 8] + lossbuf[(t + 256) * 8] +
              lossbuf[(t + 512) * 8] + lossbuf[(t + 768) * 8];
    for (int off = 32; off > 0; off >>= 1) s += __shfl_xor(s, off);
    __shared__ float ws4[4];
    if ((t & 63) == 0) ws4[t >> 6] = s;
    __syncthreads();
    if (t == 0) out_loss[0] = ws4[0] + ws4[1] + ws4[2] + ws4[3];
}

// ---------------------------------------------------------------------------
// MFMA MLP. WG = 256 thr = 4 waves, 128 columns (4 points x 32 k).
// X (96 x 128, K-padded) gathered to LDS f16; three mfma_f32_16x16x32_f16
// layers with H1/H2 LDS round-trips in [col][k] layout; fused ReLU + k-sum
// epilogue. A-frag: A[m=lane&15][k=quad*8+j]; C-frag: col=lane&15,
// row=quad*4+reg (m89/m120-verified layouts).
// ---------------------------------------------------------------------------
#define TN  128
#define XS  104    // X   stride (f16): 96 + 8 pad, 16B-aligned rows
#define H1S 136    // H1  stride: 128 + 8
#define H2S 72     // H2  stride: 64 + 8

__launch_bounds__(256, 2)
__global__ void mlp_kernel(const float4* __restrict__ pointsT,
                           const float4* __restrict__ knnT,
                           const _Float16* __restrict__ featH,
                           const int* __restrict__ idx_ws,
                           const _Float16* __restrict__ w1h, const float* __restrict__ b1,
                           const _Float16* __restrict__ w2h, const float* __restrict__ b2,
                           const _Float16* __restrict__ w3h, const float* __restrict__ b3,
                           float* __restrict__ out) {
    __shared__ __align__(16) _Float16 X[TN * XS];    // 26624 B
    __shared__ __align__(16) _Float16 H1[TN * H1S];  // 34816 B
    __shared__ __align__(16) _Float16 H2[TN * H2S];  // 18432 B

    int t = threadIdx.x;
    int point0 = blockIdx.x * 4;
    int b = point0 >> 12;            // /NN
    int n0 = point0 & (NN - 1);

    // ---- stage X tile: 2 threads per column ----
    {
        int col = t >> 1, half = t & 1;
        int pl = col >> 5, kk = col & 31;
        int n = n0 + pl;
        int id = idx_ws[(((size_t)b * NN + n) << 5) + kk];
        const v8h* src = (const v8h*)(featH + ((size_t)(b * MM + id)) * CC + half * 32);
        v8h f0 = src[0], f1 = src[1], f2 = src[2], f3 = src[3];
        v8h* dst = (v8h*)(X + col * XS + half * 32);
        dst[0] = f0; dst[1] = f1; dst[2] = f2; dst[3] = f3;
        if (half) {
            float4 p4 = pointsT[b * NN + n];
            float4 nb = knnT[b * MM + id];
            float dx = nb.x - p4.x, dy = nb.y - p4.y, dz = nb.z - p4.z;
            float dd = __fadd_rn(__fadd_rn(__fmul_rn(dx, dx), __fmul_rn(dy, dy)),
                                 __fmul_rn(dz, dz));
            v8h m0 = {(_Float16)dx, (_Float16)dy, (_Float16)dz, (_Float16)dd,
                      (_Float16)0.f, (_Float16)0.f, (_Float16)0.f, (_Float16)0.f};
            v8h z = {(_Float16)0.f, (_Float16)0.f, (_Float16)0.f, (_Float16)0.f,
                     (_Float16)0.f, (_Float16)0.f, (_Float16)0.f, (_Float16)0.f};
            v8h* md = (v8h*)(X + col * XS + 64);
            md[0] = m0; md[1] = z; md[2] = z; md[3] = z;
        }
    }

    int w = t >> 6, l = t & 63;
    int quad = l >> 4, lc = l & 15;

    // ---- preload A-fragments (weights) ----
    v8h a1[2][3], a2[4], a3[2];
#pragma unroll
    for (int rt = 0; rt < 2; ++rt)
#pragma unroll
        for (int ks = 0; ks < 3; ++ks)
            a1[rt][ks] = *(const v8h*)(w1h + (32 * w + 16 * rt + lc) * 96 + 32 * ks + 8 * quad);
#pragma unroll
    for (int ks = 0; ks < 4; ++ks)
        a2[ks] = *(const v8h*)(w2h + (16 * w + lc) * 128 + 32 * ks + 8 * quad);
#pragma unroll
    for (int ks = 0; ks < 2; ++ks)
        a3[ks] = *(const v8h*)(w3h + (16 * w + lc) * 64 + 32 * ks + 8 * quad);

    v4f bias1a = *(const v4f*)(b1 + 32 * w + 4 * quad);
    v4f bias1b = *(const v4f*)(b1 + 32 * w + 16 + 4 * quad);
    v4f bias2  = *(const v4f*)(b2 + 16 * w + 4 * quad);
    v4f bias3  = *(const v4f*)(b3 + 16 * w + 4 * quad);

    __syncthreads();

    // ---- layer 1: H1(128 x 128cols) = W1 x X ----
#pragma unroll 1
    for (int ct = 0; ct < 8; ++ct) {
        int colb = 16 * ct + lc;
        v4f acc0 = bias1a, acc1 = bias1b;
#pragma unroll
        for (int ks = 0; ks < 3; ++ks) {
            v8h bx = *(const v8h*)(X + colb * XS + 32 * ks + 8 * quad);
            acc0 = __builtin_amdgcn_mfma_f32_16x16x32_f16(a1[0][ks], bx, acc0, 0, 0, 0);
            acc1 = __builtin_amdgcn_mfma_f32_16x16x32_f16(a1[1][ks], bx, acc1, 0, 0, 0);
        }
        v4h h0, h1v;
#pragma unroll
        for (int r = 0; r < 4; ++r) {
            h0[r]  = (_Float16)fmaxf(acc0[r], 0.0f);
            h1v[r] = (_Float16)fmaxf(acc1[r], 0.0f);
        }
        *(v4h*)(H1 + colb * H1S + 32 * w + 4 * quad)      = h0;
        *(v4h*)(H1 + colb * H1S + 32 * w + 16 + 4 * quad) = h1v;
    }
    __syncthreads();

    // ---- layer 2: H2(64 x 128cols) = W2 x H1 ----
#pragma unroll 1
    for (int ct = 0; ct < 8; ++ct) {
        int colb = 16 * ct + lc;
        v4f acc = bias2;
#pragma unroll
        for (int ks = 0; ks < 4; ++ks) {
            v8h bx = *(const v8h*)(H1 + colb * H1S + 32 * ks + 8 * quad);
            acc = __builtin_amdgcn_mfma_f32_16x16x32_f16(a2[ks], bx, acc, 0, 0, 0);
        }
        v4h h;
#pragma unroll
        for (int r = 0; r < 4; ++r) h[r] = (_Float16)fmaxf(acc[r], 0.0f);
        *(v4h*)(H2 + colb * H2S + 16 * w + 4 * quad) = h;
    }
    __syncthreads();

    // ---- layer 3 + ReLU + sum over k + store agg ----
#pragma unroll 1
    for (int p = 0; p < 4; ++p) {
        int cA = (2 * p) * 16 + lc, cB = (2 * p + 1) * 16 + lc;
        v4f accA = bias3, accB = bias3;
#pragma unroll
        for (int ks = 0; ks < 2; ++ks) {
            v8h bA = *(const v8h*)(H2 + cA * H2S + 32 * ks + 8 * quad);
            v8h bB = *(const v8h*)(H2 + cB * H2S + 32 * ks + 8 * quad);
            accA = __builtin_amdgcn_mfma_f32_16x16x32_f16(a3[ks], bA, accA, 0, 0, 0);
            accB = __builtin_amdgcn_mfma_f32_16x16x32_f16(a3[ks], bB, accB, 0, 0, 0);
        }
        v4f s;
#pragma unroll
        for (int r = 0; r < 4; ++r)
            s[r] = fmaxf(accA[r], 0.0f) + fmaxf(accB[r], 0.0f);
#pragma unroll
        for (int off = 1; off < 16; off <<= 1) {
#pragma unroll
            for (int r = 0; r < 4; ++r) s[r] += __shfl_xor(s[r], off);
        }
        if (lc == 0) {
            int n = n0 + p;
            int rowb = 16 * w + 4 * quad;
#pragma unroll
            for (int r = 0; r < 4; ++r)
                out[((size_t)(b * 64 + rowb + r)) * NN + n] = s[r];
        }
    }
}

// ---------------------------------------------------------------------------
extern "C" void kernel_launch(void* const* d_in, const int* in_sizes, int n_in,
                              void* d_out, int out_size, void* d_ws, size_t ws_size,
                              hipStream_t stream) {
    const float* points = (const float*)d_in[0];
    const float* knn    = (const float*)d_in[1];
    const float* feat   = (const float*)d_in[2];
    const float* w1 = (const float*)d_in[3];
    const float* b1 = (const float*)d_in[4];
    const float* w2 = (const float*)d_in[5];
    const float* b2 = (const float*)d_in[6];
    const float* w3 = (const float*)d_in[7];
    const float* b3 = (const float*)d_in[8];
    float* out = (float*)d_out;

    char* ws = (char*)d_ws;
    float4*    pointsT = (float4*)ws;                    // 131072 B
    float4*    knnT    = (float4*)(ws + 131072);         // 131072 B
    _Float16*  featH   = (_Float16*)(ws + 262144);       // 1048576 B
    int*       idx_ws  = (int*)(ws + 1310720);           // 1048576 B
    _Float16*  w1h     = (_Float16*)(ws + 2359296);      // 24576 B
    _Float16*  w2h     = (_Float16*)(ws + 2383872);      // 16384 B
    _Float16*  w3h     = (_Float16*)(ws + 2400256);      // 8192 B
    float*     lossbuf = (float*)(ws + 2408448);         // 32768 B

    float* loss_out = out + (size_t)BB * 64 * NN;

    hipMemsetAsync(lossbuf, 0, 32768, stream);
    prep_pts_kernel<<<(BB * NN + 255) / 256, 256, 0, stream>>>(points, pointsT, NN);
    prep_pts_kernel<<<(BB * MM + 255) / 256, 256, 0, stream>>>(knn, knnT, MM);
    pack_w_kernel<<<48, 256, 0, stream>>>(w1, w2, w3, w1h, w2h, w3h);
    transpose_feat_kernel<<<BB * (MM / 64), 256, 0, stream>>>(feat, featH);
    select_kernel<<<BB * NN, 64, 0, stream>>>(pointsT, knnT, idx_ws, lossbuf);
    colmin_kernel<<<BB * MM, 64, 0, stream>>>(pointsT, knnT, lossbuf);
    loss_reduce_kernel<<<1, 256, 0, stream>>>(lossbuf, loss_out);
    mlp_kernel<<<(BB * NN) / 4, 256, 0, stream>>>(pointsT, knnT, featH, idx_ws,
                                                  w1h, b1, w2h, b2, w3h, b3, out);
}

// Round 4
// 137.420 us; speedup vs baseline: 5.6583x; 1.1382x over previous
//
#include <hip/hip_runtime.h>
#include <cstdint>

#define BB 2
#define NN 4096
#define MM 4096
#define KK 32
#define CC 64
#define R2C 0.0064f   // RADIUS^2

typedef _Float16 v8h __attribute__((ext_vector_type(8)));
typedef _Float16 v4h __attribute__((ext_vector_type(4)));
typedef float    v4f __attribute__((ext_vector_type(4)));

// ---------------------------------------------------------------------------
// Fused setup: one dispatch does all preprocessing.
//   blocks [  0, 32): pack points  (B,3,N)->float4{x,y,z,|p|^2}  (strict fp32)
//   blocks [ 32, 64): pack knn     (B,3,M)->float4
//   blocks [ 64,192): transpose feat (B,C,M) -> featH (B,M,C) f16
//   blocks [192,240): pack weights to f16 A-operand layouts
//   blocks [240,248): zero the 1024-slot loss partial buffer
// ---------------------------------------------------------------------------
__launch_bounds__(256)
__global__ void setup_kernel(const float* __restrict__ points,
                             const float* __restrict__ knn,
                             const float* __restrict__ feat,
                             const float* __restrict__ w1,
                             const float* __restrict__ w2,
                             const float* __restrict__ w3,
                             float4* __restrict__ pointsT,
                             float4* __restrict__ knnT,
                             _Float16* __restrict__ featH,
                             _Float16* __restrict__ w1h,
                             _Float16* __restrict__ w2h,
                             _Float16* __restrict__ w3h,
                             float* __restrict__ lossbuf) {
    __shared__ float tile[64][65];
    int blk = blockIdx.x, t = threadIdx.x;
    if (blk < 64) {
        const float* src = (blk < 32) ? points : knn;
        float4* dst = (blk < 32) ? pointsT : knnT;
        int i = (blk & 31) * 256 + t;          // < 8192 = BB*4096
        int b = i >> 12, p = i & 4095;
        const float* base = src + (size_t)b * 3 * 4096;
        float x = base[p], y = base[4096 + p], z = base[8192 + p];
        float e = __fadd_rn(__fadd_rn(__fmul_rn(x, x), __fmul_rn(y, y)),
                            __fmul_rn(z, z));
        dst[i] = make_float4(x, y, z, e);
    } else if (blk < 192) {
        int tb = blk - 64;                      // 128 tiles
        int b = tb / (MM / 64);
        int m0 = (tb % (MM / 64)) * 64;
        int mi = t & 63, cq = t >> 6;
        const float* src = feat + (size_t)b * CC * MM;
#pragma unroll
        for (int r = 0; r < 16; ++r) {
            int c = cq * 16 + r;
            tile[mi][c] = src[(size_t)c * MM + m0 + mi];
        }
        __syncthreads();
        int ci = t & 63, mq = t >> 6;
        _Float16* dst = featH + ((size_t)b * MM + m0) * CC;
#pragma unroll
        for (int r = 0; r < 16; ++r) {
            int mm = mq * 16 + r;
            dst[(size_t)mm * CC + ci] = (_Float16)tile[mm][ci];
        }
    } else if (blk < 240) {
        int tt = (blk - 192) * 256 + t;         // < 12288
        if (tt < 128 * 96) {
            int r = tt / 96, k = tt - r * 96;
            w1h[tt] = (_Float16)((k < 68) ? w1[r * 68 + k] : 0.0f);
        }
        if (tt < 64 * 128) w2h[tt] = (_Float16)w2[tt];
        if (tt < 64 * 64)  w3h[tt] = (_Float16)w3[tt];
    } else {
        int i = ((blk - 240) * 256 + t) * 4;    // zero 8192 floats
        *(float4*)(lossbuf + i) = make_float4(0.f, 0.f, 0.f, 0.f);
    }
}

// ---------------------------------------------------------------------------
// Selection: 4 waves/block, 1 wave per (b,n). Ballot + stream-compact the
// first KK in-radius indices (ascending m == reference top_k-of-masked-index).
// Row-min -> loss partial (1024 spread slots, 32B stride).
// ---------------------------------------------------------------------------
__launch_bounds__(256)
__global__ void select_kernel(const float4* __restrict__ pointsT,
                              const float4* __restrict__ knnT,
                              int* __restrict__ idx_ws,
                              float* __restrict__ lossbuf) {
    __shared__ int sidx[4][KK];
    int t = threadIdx.x;
    int w = t >> 6, lane = t & 63;
    int pt = blockIdx.x * 4 + w;     // b*NN + n
    int b = pt >> 12;
    float4 p4 = pointsT[pt];
    const float4* kb = knnT + (size_t)b * MM;
    int cnt = 0;
    float minD = 1e30f;
    for (int c = 0; c < MM / 64; ++c) {
        int m = c * 64 + lane;
        float4 k4 = kb[m];
        float cross = __builtin_fmaf(p4.z, k4.z,
                      __builtin_fmaf(p4.y, k4.y, __fmul_rn(p4.x, k4.x)));
        float d2 = __fsub_rn(__fadd_rn(p4.w, k4.w), __fmul_rn(2.0f, cross));
        bool hit = d2 < R2C;
        minD = fminf(minD, fmaxf(d2, 0.0f));
        unsigned long long mask = __ballot(hit);
        if (hit) {
            int pos = cnt + __builtin_amdgcn_mbcnt_hi(
                              (unsigned)(mask >> 32),
                              __builtin_amdgcn_mbcnt_lo((unsigned)mask, 0));
            if (pos < KK) sidx[w][pos] = m;
        }
        cnt += __popcll(mask);
    }
    __syncthreads();
    if (lane < KK) {
        int fillv = (cnt > 0) ? sidx[w][0] : 0;
        int v = (lane < cnt) ? sidx[w][lane] : fillv;
        idx_ws[(size_t)pt * KK + lane] = v;
    }
    for (int off = 32; off > 0; off >>= 1)
        minD = fminf(minD, __shfl_xor(minD, off));
    if (lane == 0)
        atomicAdd(lossbuf + (pt & 1023) * 8,
                  sqrtf(1e-6f + minD) * (1.0f / (BB * NN)));
}

// ---------------------------------------------------------------------------
// Column min: 4 waves/block, 2 m per wave (shared p4 loads, 2x ILP).
// ---------------------------------------------------------------------------
__launch_bounds__(256)
__global__ void colmin_kernel(const float4* __restrict__ pointsT,
                              const float4* __restrict__ knnT,
                              float* __restrict__ lossbuf) {
    int t = threadIdx.x;
    int w = t >> 6, lane = t & 63;
    int mp = blockIdx.x * 8 + w * 2;  // b*MM + m (even)
    int b = mp >> 12;
    float4 kA = knnT[mp], kB = knnT[mp + 1];
    const float4* pb = pointsT + (size_t)b * NN;
    float minA = 1e30f, minB = 1e30f;
    for (int c = 0; c < NN / 64; ++c) {
        float4 p4 = pb[c * 64 + lane];
        float crA = __builtin_fmaf(p4.z, kA.z,
                    __builtin_fmaf(p4.y, kA.y, __fmul_rn(p4.x, kA.x)));
        float crB = __builtin_fmaf(p4.z, kB.z,
                    __builtin_fmaf(p4.y, kB.y, __fmul_rn(p4.x, kB.x)));
        float dA = __fsub_rn(__fadd_rn(p4.w, kA.w), __fmul_rn(2.0f, crA));
        float dB = __fsub_rn(__fadd_rn(p4.w, kB.w), __fmul_rn(2.0f, crB));
        minA = fminf(minA, fmaxf(dA, 0.0f));
        minB = fminf(minB, fmaxf(dB, 0.0f));
    }
    for (int off = 32; off > 0; off >>= 1) {
        minA = fminf(minA, __shfl_xor(minA, off));
        minB = fminf(minB, __shfl_xor(minB, off));
    }
    if (lane == 0)
        atomicAdd(lossbuf + ((mp >> 1) & 1023) * 8,
                  (sqrtf(1e-6f + minA) + sqrtf(1e-6f + minB)) * (1.0f / (BB * MM)));
}

// ---------------------------------------------------------------------------
// MFMA MLP. WG = 256 thr = 4 waves, 128 columns (4 points x 32 k).
// X (96 x 128, K-padded) gathered to LDS f16; three mfma_f32_16x16x32_f16
// layers with H1/H2 LDS round-trips in [col][k] layout; fused ReLU + k-sum
// epilogue. Block 0 additionally sums the loss partials (stream order
// guarantees select/colmin completed). A-frag: A[m=lane&15][k=quad*8+j];
// C-frag: col=lane&15, row=quad*4+reg (m89/m120-verified layouts).
// ---------------------------------------------------------------------------
#define TN  128
#define XS  104    // X  stride (f16): 96 + 8 pad
#define H1S 136    // H1 stride: 128 + 8
#define H2S 72     // H2 stride: 64 + 8

__launch_bounds__(256, 2)
__global__ void mlp_kernel(const float4* __restrict__ pointsT,
                           const float4* __restrict__ knnT,
                           const _Float16* __restrict__ featH,
                           const int* __restrict__ idx_ws,
                           const _Float16* __restrict__ w1h, const float* __restrict__ b1,
                           const _Float16* __restrict__ w2h, const float* __restrict__ b2,
                           const _Float16* __restrict__ w3h, const float* __restrict__ b3,
                           const float* __restrict__ lossbuf,
                           float* __restrict__ out) {
    __shared__ __align__(16) _Float16 X[TN * XS];
    __shared__ __align__(16) _Float16 H1[TN * H1S];
    __shared__ __align__(16) _Float16 H2[TN * H2S];
    __shared__ float ws4[4];

    int t = threadIdx.x;

    // ---- fused loss reduction (block 0 only) ----
    if (blockIdx.x == 0) {
        float s = lossbuf[t * 8] + lossbuf[(t + 256) * 8] +
                  lossbuf[(t + 512) * 8] + lossbuf[(t + 768) * 8];
        for (int off = 32; off > 0; off >>= 1) s += __shfl_xor(s, off);
        if ((t & 63) == 0) ws4[t >> 6] = s;
        __syncthreads();
        if (t == 0)
            out[(size_t)BB * 64 * NN] = ws4[0] + ws4[1] + ws4[2] + ws4[3];
    }

    int point0 = blockIdx.x * 4;
    int b = point0 >> 12;
    int n0 = point0 & (NN - 1);

    // ---- stage X tile: 2 threads per column ----
    {
        int col = t >> 1, half = t & 1;
        int pl = col >> 5, kk = col & 31;
        int n = n0 + pl;
        int id = idx_ws[(((size_t)b * NN + n) << 5) + kk];
        const v8h* src = (const v8h*)(featH + ((size_t)(b * MM + id)) * CC + half * 32);
        v8h f0 = src[0], f1 = src[1], f2 = src[2], f3 = src[3];
        v8h* dst = (v8h*)(X + col * XS + half * 32);
        dst[0] = f0; dst[1] = f1; dst[2] = f2; dst[3] = f3;
        if (half) {
            float4 p4 = pointsT[b * NN + n];
            float4 nb = knnT[b * MM + id];
            float dx = nb.x - p4.x, dy = nb.y - p4.y, dz = nb.z - p4.z;
            float dd = __fadd_rn(__fadd_rn(__fmul_rn(dx, dx), __fmul_rn(dy, dy)),
                                 __fmul_rn(dz, dz));
            v8h m0 = {(_Float16)dx, (_Float16)dy, (_Float16)dz, (_Float16)dd,
                      (_Float16)0.f, (_Float16)0.f, (_Float16)0.f, (_Float16)0.f};
            v8h z = {(_Float16)0.f, (_Float16)0.f, (_Float16)0.f, (_Float16)0.f,
                     (_Float16)0.f, (_Float16)0.f, (_Float16)0.f, (_Float16)0.f};
            v8h* md = (v8h*)(X + col * XS + 64);
            md[0] = m0; md[1] = z; md[2] = z; md[3] = z;
        }
    }

    int w = t >> 6, l = t & 63;
    int quad = l >> 4, lc = l & 15;

    // ---- preload A-fragments (weights) ----
    v8h a1[2][3], a2[4], a3[2];
#pragma unroll
    for (int rt = 0; rt < 2; ++rt)
#pragma unroll
        for (int ks = 0; ks < 3; ++ks)
            a1[rt][ks] = *(const v8h*)(w1h + (32 * w + 16 * rt + lc) * 96 + 32 * ks + 8 * quad);
#pragma unroll
    for (int ks = 0; ks < 4; ++ks)
        a2[ks] = *(const v8h*)(w2h + (16 * w + lc) * 128 + 32 * ks + 8 * quad);
#pragma unroll
    for (int ks = 0; ks < 2; ++ks)
        a3[ks] = *(const v8h*)(w3h + (16 * w + lc) * 64 + 32 * ks + 8 * quad);

    v4f bias1a = *(const v4f*)(b1 + 32 * w + 4 * quad);
    v4f bias1b = *(const v4f*)(b1 + 32 * w + 16 + 4 * quad);
    v4f bias2  = *(const v4f*)(b2 + 16 * w + 4 * quad);
    v4f bias3  = *(const v4f*)(b3 + 16 * w + 4 * quad);

    __syncthreads();

    // ---- layer 1: H1(128 x 128cols) = W1 x X ----
#pragma unroll 1
    for (int ct = 0; ct < 8; ++ct) {
        int colb = 16 * ct + lc;
        v4f acc0 = bias1a, acc1 = bias1b;
#pragma unroll
        for (int ks = 0; ks < 3; ++ks) {
            v8h bx = *(const v8h*)(X + colb * XS + 32 * ks + 8 * quad);
            acc0 = __builtin_amdgcn_mfma_f32_16x16x32_f16(a1[0][ks], bx, acc0, 0, 0, 0);
            acc1 = __builtin_amdgcn_mfma_f32_16x16x32_f16(a1[1][ks], bx, acc1, 0, 0, 0);
        }
        v4h h0, h1v;
#pragma unroll
        for (int r = 0; r < 4; ++r) {
            h0[r]  = (_Float16)fmaxf(acc0[r], 0.0f);
            h1v[r] = (_Float16)fmaxf(acc1[r], 0.0f);
        }
        *(v4h*)(H1 + colb * H1S + 32 * w + 4 * quad)      = h0;
        *(v4h*)(H1 + colb * H1S + 32 * w + 16 + 4 * quad) = h1v;
    }
    __syncthreads();

    // ---- layer 2: H2(64 x 128cols) = W2 x H1 ----
#pragma unroll 1
    for (int ct = 0; ct < 8; ++ct) {
        int colb = 16 * ct + lc;
        v4f acc = bias2;
#pragma unroll
        for (int ks = 0; ks < 4; ++ks) {
            v8h bx = *(const v8h*)(H1 + colb * H1S + 32 * ks + 8 * quad);
            acc = __builtin_amdgcn_mfma_f32_16x16x32_f16(a2[ks], bx, acc, 0, 0, 0);
        }
        v4h h;
#pragma unroll
        for (int r = 0; r < 4; ++r) h[r] = (_Float16)fmaxf(acc[r], 0.0f);
        *(v4h*)(H2 + colb * H2S + 16 * w + 4 * quad) = h;
    }
    __syncthreads();

    // ---- layer 3 + ReLU + sum over k + store agg ----
#pragma unroll 1
    for (int p = 0; p < 4; ++p) {
        int cA = (2 * p) * 16 + lc, cB = (2 * p + 1) * 16 + lc;
        v4f accA = bias3, accB = bias3;
#pragma unroll
        for (int ks = 0; ks < 2; ++ks) {
            v8h bA = *(const v8h*)(H2 + cA * H2S + 32 * ks + 8 * quad);
            v8h bB = *(const v8h*)(H2 + cB * H2S + 32 * ks + 8 * quad);
            accA = __builtin_amdgcn_mfma_f32_16x16x32_f16(a3[ks], bA, accA, 0, 0, 0);
            accB = __builtin_amdgcn_mfma_f32_16x16x32_f16(a3[ks], bB, accB, 0, 0, 0);
        }
        v4f s;
#pragma unroll
        for (int r = 0; r < 4; ++r)
            s[r] = fmaxf(accA[r], 0.0f) + fmaxf(accB[r], 0.0f);
#pragma unroll
        for (int off = 1; off < 16; off <<= 1) {
#pragma unroll
            for (int r = 0; r < 4; ++r) s[r] += __shfl_xor(s[r], off);
        }
        if (lc == 0) {
            int n = n0 + p;
            int rowb = 16 * w + 4 * quad;
#pragma unroll
            for (int r = 0; r < 4; ++r)
                out[((size_t)(b * 64 + rowb + r)) * NN + n] = s[r];
        }
    }
}

// ---------------------------------------------------------------------------
extern "C" void kernel_launch(void* const* d_in, const int* in_sizes, int n_in,
                              void* d_out, int out_size, void* d_ws, size_t ws_size,
                              hipStream_t stream) {
    const float* points = (const float*)d_in[0];
    const float* knn    = (const float*)d_in[1];
    const float* feat   = (const float*)d_in[2];
    const float* w1 = (const float*)d_in[3];
    const float* b1 = (const float*)d_in[4];
    const float* w2 = (const float*)d_in[5];
    const float* b2 = (const float*)d_in[6];
    const float* w3 = (const float*)d_in[7];
    const float* b3 = (const float*)d_in[8];
    float* out = (float*)d_out;

    char* ws = (char*)d_ws;
    float4*    pointsT = (float4*)ws;                    // 131072 B
    float4*    knnT    = (float4*)(ws + 131072);         // 131072 B
    _Float16*  featH   = (_Float16*)(ws + 262144);       // 1048576 B
    int*       idx_ws  = (int*)(ws + 1310720);           // 1048576 B
    _Float16*  w1h     = (_Float16*)(ws + 2359296);      // 24576 B
    _Float16*  w2h     = (_Float16*)(ws + 2383872);      // 16384 B
    _Float16*  w3h     = (_Float16*)(ws + 2400256);      // 8192 B
    float*     lossbuf = (float*)(ws + 2408448);         // 32768 B

    setup_kernel<<<248, 256, 0, stream>>>(points, knn, feat, w1, w2, w3,
                                          pointsT, knnT, featH, w1h, w2h, w3h,
                                          lossbuf);
    select_kernel<<<(BB * NN) / 4, 256, 0, stream>>>(pointsT, knnT, idx_ws, lossbuf);
    colmin_kernel<<<(BB * MM) / 8, 256, 0, stream>>>(pointsT, knnT, lossbuf);
    mlp_kernel<<<(BB * NN) / 4, 256, 0, stream>>>(pointsT, knnT, featH, idx_ws,
                                                  w1h, b1, w2h, b2, w3h, b3,
                                                  lossbuf, out);
}

// Round 5
// 121.406 us; speedup vs baseline: 6.4047x; 1.1319x over previous
//
#include <hip/hip_runtime.h>
#include <cstdint>

#define BB 2
#define NN 4096
#define MM 4096
#define KK 32
#define CC 64
#define R2C 0.0064f   // RADIUS^2

typedef _Float16 v8h __attribute__((ext_vector_type(8)));
typedef _Float16 v4h __attribute__((ext_vector_type(4)));
typedef float    v4f __attribute__((ext_vector_type(4)));

// ---------------------------------------------------------------------------
// Fused setup: one dispatch does all preprocessing.
//   blocks [  0, 32): pack points  (B,3,N)->float4{x,y,z,|p|^2}  (strict fp32)
//   blocks [ 32, 64): pack knn     (B,3,M)->float4
//   blocks [ 64,192): transpose feat (B,C,M) -> featH (B,M,C) f16
//   blocks [192,240): pack weights to f16 A-operand layouts
//   blocks [240,248): zero the 1024-slot loss partial buffer
// ---------------------------------------------------------------------------
__launch_bounds__(256)
__global__ void setup_kernel(const float* __restrict__ points,
                             const float* __restrict__ knn,
                             const float* __restrict__ feat,
                             const float* __restrict__ w1,
                             const float* __restrict__ w2,
                             const float* __restrict__ w3,
                             float4* __restrict__ pointsT,
                             float4* __restrict__ knnT,
                             _Float16* __restrict__ featH,
                             _Float16* __restrict__ w1h,
                             _Float16* __restrict__ w2h,
                             _Float16* __restrict__ w3h,
                             float* __restrict__ lossbuf) {
    __shared__ float tile[64][65];
    int blk = blockIdx.x, t = threadIdx.x;
    if (blk < 64) {
        const float* src = (blk < 32) ? points : knn;
        float4* dst = (blk < 32) ? pointsT : knnT;
        int i = (blk & 31) * 256 + t;          // < 8192 = BB*4096
        int b = i >> 12, p = i & 4095;
        const float* base = src + (size_t)b * 3 * 4096;
        float x = base[p], y = base[4096 + p], z = base[8192 + p];
        float e = __fadd_rn(__fadd_rn(__fmul_rn(x, x), __fmul_rn(y, y)),
                            __fmul_rn(z, z));
        dst[i] = make_float4(x, y, z, e);
    } else if (blk < 192) {
        int tb = blk - 64;                      // 128 tiles
        int b = tb / (MM / 64);
        int m0 = (tb % (MM / 64)) * 64;
        int mi = t & 63, cq = t >> 6;
        const float* src = feat + (size_t)b * CC * MM;
#pragma unroll
        for (int r = 0; r < 16; ++r) {
            int c = cq * 16 + r;
            tile[mi][c] = src[(size_t)c * MM + m0 + mi];
        }
        __syncthreads();
        int ci = t & 63, mq = t >> 6;
        _Float16* dst = featH + ((size_t)b * MM + m0) * CC;
#pragma unroll
        for (int r = 0; r < 16; ++r) {
            int mm = mq * 16 + r;
            dst[(size_t)mm * CC + ci] = (_Float16)tile[mm][ci];
        }
    } else if (blk < 240) {
        int tt = (blk - 192) * 256 + t;         // < 12288
        if (tt < 128 * 96) {
            int r = tt / 96, k = tt - r * 96;
            w1h[tt] = (_Float16)((k < 68) ? w1[r * 68 + k] : 0.0f);
        }
        if (tt < 64 * 128) w2h[tt] = (_Float16)w2[tt];
        if (tt < 64 * 64)  w3h[tt] = (_Float16)w3[tt];
    } else {
        int i = ((blk - 240) * 256 + t) * 4;    // zero 8192 floats
        *(float4*)(lossbuf + i) = make_float4(0.f, 0.f, 0.f, 0.f);
    }
}

// ---------------------------------------------------------------------------
// Fused scan: one dispatch for ball-query selection AND both loss min-scans.
//   blocks [  0, 512): select — 16 points/block (4/wave); knnT chunks staged
//                      to LDS (4 x 16 KB); ballot-compaction of first-KK
//                      in-radius indices (ascending m == ref top_k semantics);
//                      row-min -> loss partial.
//   blocks [512,1024): colmin — 16 m/block (4/wave); pointsT chunks staged;
//                      col-min -> loss partial.
// Global traffic: 64 KB/block instead of 64 KB/wave-point (16x less).
// d2 math strict fp32, identical op order to reference.
// ---------------------------------------------------------------------------
__launch_bounds__(256)
__global__ void scan_kernel(const float4* __restrict__ pointsT,
                            const float4* __restrict__ knnT,
                            int* __restrict__ idx_ws,
                            float* __restrict__ lossbuf) {
    __shared__ float4 tile[1024];    // 16 KB staging
    __shared__ int sidx[16][KK];     // select only
    int t = threadIdx.x;
    int w = t >> 6, lane = t & 63;
    int blk = blockIdx.x;

    if (blk < 512) {
        // ---------------- select ----------------
        int pt0 = blk * 16;                  // global point base (b*NN+n)
        int b = pt0 >> 12;
        float4 P[4];
#pragma unroll
        for (int p = 0; p < 4; ++p) P[p] = pointsT[pt0 + 4 * w + p];
        int cnt[4] = {0, 0, 0, 0};
        float mn[4] = {1e30f, 1e30f, 1e30f, 1e30f};
        const float4* kb = knnT + (size_t)b * MM;

        for (int ch = 0; ch < 4; ++ch) {
            const float4* src = kb + ch * 1024;
            tile[t] = src[t]; tile[t + 256] = src[t + 256];
            tile[t + 512] = src[t + 512]; tile[t + 768] = src[t + 768];
            __syncthreads();
#pragma unroll 2
            for (int i = 0; i < 16; ++i) {
                float4 k4 = tile[i * 64 + lane];
                int m = ch * 1024 + i * 64 + lane;
#pragma unroll
                for (int p = 0; p < 4; ++p) {
                    float cross = __builtin_fmaf(P[p].z, k4.z,
                                  __builtin_fmaf(P[p].y, k4.y,
                                                 __fmul_rn(P[p].x, k4.x)));
                    float d2 = __fsub_rn(__fadd_rn(P[p].w, k4.w),
                                         __fmul_rn(2.0f, cross));
                    mn[p] = fminf(mn[p], fmaxf(d2, 0.0f));
                    bool hit = d2 < R2C;
                    unsigned long long mask = __ballot(hit);
                    if (hit) {
                        int pos = cnt[p] + __builtin_amdgcn_mbcnt_hi(
                                     (unsigned)(mask >> 32),
                                     __builtin_amdgcn_mbcnt_lo((unsigned)mask, 0));
                        if (pos < KK) sidx[4 * w + p][pos] = m;
                    }
                    cnt[p] += __popcll(mask);
                }
            }
            __syncthreads();
        }

        float lsum = 0.0f;
#pragma unroll
        for (int p = 0; p < 4; ++p) {
            if (lane < KK) {
                int row = 4 * w + p;
                int fillv = (cnt[p] > 0) ? sidx[row][0] : 0;
                int v = (lane < cnt[p]) ? sidx[row][lane] : fillv;
                idx_ws[((size_t)(pt0 + row)) * KK + lane] = v;
            }
            float mv = mn[p];
            for (int off = 32; off > 0; off >>= 1)
                mv = fminf(mv, __shfl_xor(mv, off));
            lsum += sqrtf(1e-6f + mv);
        }
        if (lane == 0)
            atomicAdd(lossbuf + ((blk * 4 + w) & 1023) * 8,
                      lsum * (1.0f / (BB * NN)));
    } else {
        // ---------------- colmin ----------------
        int blk2 = blk - 512;
        int m0 = blk2 * 16;                  // global knn base (b*MM+m)
        int b = m0 >> 12;
        float4 Kp[4];
#pragma unroll
        for (int p = 0; p < 4; ++p) Kp[p] = knnT[m0 + 4 * w + p];
        float mn[4] = {1e30f, 1e30f, 1e30f, 1e30f};
        const float4* pb = pointsT + (size_t)b * NN;

        for (int ch = 0; ch < 4; ++ch) {
            const float4* src = pb + ch * 1024;
            tile[t] = src[t]; tile[t + 256] = src[t + 256];
            tile[t + 512] = src[t + 512]; tile[t + 768] = src[t + 768];
            __syncthreads();
#pragma unroll 2
            for (int i = 0; i < 16; ++i) {
                float4 p4 = tile[i * 64 + lane];
#pragma unroll
                for (int p = 0; p < 4; ++p) {
                    float cross = __builtin_fmaf(p4.z, Kp[p].z,
                                  __builtin_fmaf(p4.y, Kp[p].y,
                                                 __fmul_rn(p4.x, Kp[p].x)));
                    float d2 = __fsub_rn(__fadd_rn(p4.w, Kp[p].w),
                                         __fmul_rn(2.0f, cross));
                    mn[p] = fminf(mn[p], fmaxf(d2, 0.0f));
                }
            }
            __syncthreads();
        }

        float lsum = 0.0f;
#pragma unroll
        for (int p = 0; p < 4; ++p) {
            float mv = mn[p];
            for (int off = 32; off > 0; off >>= 1)
                mv = fminf(mv, __shfl_xor(mv, off));
            lsum += sqrtf(1e-6f + mv);
        }
        if (lane == 0)
            atomicAdd(lossbuf + ((blk2 * 4 + w) & 1023) * 8,
                      lsum * (1.0f / (BB * MM)));
    }
}

// ---------------------------------------------------------------------------
// MFMA MLP. WG = 256 thr = 4 waves, 64 columns (2 points x 32 k).
// LDS: H2 aliases X (X dead after the layer-1 barrier) -> 30720 B/block,
// 4 blocks/CU (16 waves/CU vs 8 in the 128-col version).
// X (96 x 64, K-padded) gathered to LDS f16; three mfma_f32_16x16x32_f16
// layers; fused ReLU + k-sum epilogue; block 0 sums the loss partials.
// A-frag: A[m=lane&15][k=quad*8+j]; C-frag: col=lane&15, row=quad*4+reg.
// ---------------------------------------------------------------------------
#define TC  64     // columns per block
#define XS  104    // X  stride (f16): 96 + 8 pad
#define H1S 136    // H1 stride: 128 + 8
#define H2S 72     // H2 stride: 64 + 8

__launch_bounds__(256, 4)
__global__ void mlp_kernel(const float4* __restrict__ pointsT,
                           const float4* __restrict__ knnT,
                           const _Float16* __restrict__ featH,
                           const int* __restrict__ idx_ws,
                           const _Float16* __restrict__ w1h, const float* __restrict__ b1,
                           const _Float16* __restrict__ w2h, const float* __restrict__ b2,
                           const _Float16* __restrict__ w3h, const float* __restrict__ b3,
                           const float* __restrict__ lossbuf,
                           float* __restrict__ out) {
    __shared__ __align__(16) _Float16 SM[TC * XS + TC * H1S];  // 30720 B
    _Float16* X  = SM;            // [TC][XS]
    _Float16* H2 = SM;            // aliases X (X dead after layer-1 barrier)
    _Float16* H1 = SM + TC * XS;  // [TC][H1S]
    __shared__ float ws4[4];

    int t = threadIdx.x;

    // ---- fused loss reduction (block 0 only) ----
    if (blockIdx.x == 0) {
        float s = lossbuf[t * 8] + lossbuf[(t + 256) * 8] +
                  lossbuf[(t + 512) * 8] + lossbuf[(t + 768) * 8];
        for (int off = 32; off > 0; off >>= 1) s += __shfl_xor(s, off);
        if ((t & 63) == 0) ws4[t >> 6] = s;
        __syncthreads();
        if (t == 0)
            out[(size_t)BB * 64 * NN] = ws4[0] + ws4[1] + ws4[2] + ws4[3];
    }

    int point0 = blockIdx.x * 2;
    int b = point0 >> 12;
    int n0 = point0 & (NN - 1);

    // ---- stage X tile: 4 threads per column ----
    {
        int col = t >> 2, h = t & 3;
        int pl = col >> 5, kk = col & 31;
        int n = n0 + pl;
        int id = idx_ws[(((size_t)b * NN + n) << 5) + kk];
        const v8h* src = (const v8h*)(featH + ((size_t)(b * MM + id)) * CC) + h * 2;
        v8h f0 = src[0], f1 = src[1];
        v8h* dst = (v8h*)(X + col * XS) + h * 2;
        dst[0] = f0; dst[1] = f1;
        v8h mv = {(_Float16)0.f, (_Float16)0.f, (_Float16)0.f, (_Float16)0.f,
                  (_Float16)0.f, (_Float16)0.f, (_Float16)0.f, (_Float16)0.f};
        if (h == 0) {
            float4 p4 = pointsT[b * NN + n];
            float4 nb = knnT[b * MM + id];
            float dx = nb.x - p4.x, dy = nb.y - p4.y, dz = nb.z - p4.z;
            float dd = __fadd_rn(__fadd_rn(__fmul_rn(dx, dx), __fmul_rn(dy, dy)),
                                 __fmul_rn(dz, dz));
            mv[0] = (_Float16)dx; mv[1] = (_Float16)dy;
            mv[2] = (_Float16)dz; mv[3] = (_Float16)dd;
        }
        *((v8h*)(X + col * XS + 64) + h) = mv;   // meta + zero-pad [64,96)
    }

    int w = t >> 6, l = t & 63;
    int quad = l >> 4, lc = l & 15;

    // ---- preload A-fragments (weights) ----
    v8h a1[2][3], a2[4], a3[2];
#pragma unroll
    for (int rt = 0; rt < 2; ++rt)
#pragma unroll
        for (int ks = 0; ks < 3; ++ks)
            a1[rt][ks] = *(const v8h*)(w1h + (32 * w + 16 * rt + lc) * 96 + 32 * ks + 8 * quad);
#pragma unroll
    for (int ks = 0; ks < 4; ++ks)
        a2[ks] = *(const v8h*)(w2h + (16 * w + lc) * 128 + 32 * ks + 8 * quad);
#pragma unroll
    for (int ks = 0; ks < 2; ++ks)
        a3[ks] = *(const v8h*)(w3h + (16 * w + lc) * 64 + 32 * ks + 8 * quad);

    v4f bias1a = *(const v4f*)(b1 + 32 * w + 4 * quad);
    v4f bias1b = *(const v4f*)(b1 + 32 * w + 16 + 4 * quad);
    v4f bias2  = *(const v4f*)(b2 + 16 * w + 4 * quad);
    v4f bias3  = *(const v4f*)(b3 + 16 * w + 4 * quad);

    __syncthreads();

    // ---- layer 1: H1(128 x 64cols) = W1 x X ----
#pragma unroll 1
    for (int ct = 0; ct < 4; ++ct) {
        int colb = 16 * ct + lc;
        v4f acc0 = bias1a, acc1 = bias1b;
#pragma unroll
        for (int ks = 0; ks < 3; ++ks) {
            v8h bx = *(const v8h*)(X + colb * XS + 32 * ks + 8 * quad);
            acc0 = __builtin_amdgcn_mfma_f32_16x16x32_f16(a1[0][ks], bx, acc0, 0, 0, 0);
            acc1 = __builtin_amdgcn_mfma_f32_16x16x32_f16(a1[1][ks], bx, acc1, 0, 0, 0);
        }
        v4h h0, h1v;
#pragma unroll
        for (int r = 0; r < 4; ++r) {
            h0[r]  = (_Float16)fmaxf(acc0[r], 0.0f);
            h1v[r] = (_Float16)fmaxf(acc1[r], 0.0f);
        }
        *(v4h*)(H1 + colb * H1S + 32 * w + 4 * quad)      = h0;
        *(v4h*)(H1 + colb * H1S + 32 * w + 16 + 4 * quad) = h1v;
    }
    __syncthreads();   // X fully consumed; H2 may now overwrite it

    // ---- layer 2: H2(64 x 64cols) = W2 x H1 ----
#pragma unroll 1
    for (int ct = 0; ct < 4; ++ct) {
        int colb = 16 * ct + lc;
        v4f acc = bias2;
#pragma unroll
        for (int ks = 0; ks < 4; ++ks) {
            v8h bx = *(const v8h*)(H1 + colb * H1S + 32 * ks + 8 * quad);
            acc = __builtin_amdgcn_mfma_f32_16x16x32_f16(a2[ks], bx, acc, 0, 0, 0);
        }
        v4h h;
#pragma unroll
        for (int r = 0; r < 4; ++r) h[r] = (_Float16)fmaxf(acc[r], 0.0f);
        *(v4h*)(H2 + colb * H2S + 16 * w + 4 * quad) = h;
    }
    __syncthreads();

    // ---- layer 3 + ReLU + sum over k + store agg ----
#pragma unroll 1
    for (int p = 0; p < 2; ++p) {
        int cA = (2 * p) * 16 + lc, cB = (2 * p + 1) * 16 + lc;
        v4f accA = bias3, accB = bias3;
#pragma unroll
        for (int ks = 0; ks < 2; ++ks) {
            v8h bA = *(const v8h*)(H2 + cA * H2S + 32 * ks + 8 * quad);
            v8h bB = *(const v8h*)(H2 + cB * H2S + 32 * ks + 8 * quad);
            accA = __builtin_amdgcn_mfma_f32_16x16x32_f16(a3[ks], bA, accA, 0, 0, 0);
            accB = __builtin_amdgcn_mfma_f32_16x16x32_f16(a3[ks], bB, accB, 0, 0, 0);
        }
        v4f s;
#pragma unroll
        for (int r = 0; r < 4; ++r)
            s[r] = fmaxf(accA[r], 0.0f) + fmaxf(accB[r], 0.0f);
#pragma unroll
        for (int off = 1; off < 16; off <<= 1) {
#pragma unroll
            for (int r = 0; r < 4; ++r) s[r] += __shfl_xor(s[r], off);
        }
        if (lc == 0) {
            int n = n0 + p;
            int rowb = 16 * w + 4 * quad;
#pragma unroll
            for (int r = 0; r < 4; ++r)
                out[((size_t)(b * 64 + rowb + r)) * NN + n] = s[r];
        }
    }
}

// ---------------------------------------------------------------------------
extern "C" void kernel_launch(void* const* d_in, const int* in_sizes, int n_in,
                              void* d_out, int out_size, void* d_ws, size_t ws_size,
                              hipStream_t stream) {
    const float* points = (const float*)d_in[0];
    const float* knn    = (const float*)d_in[1];
    const float* feat   = (const float*)d_in[2];
    const float* w1 = (const float*)d_in[3];
    const float* b1 = (const float*)d_in[4];
    const float* w2 = (const float*)d_in[5];
    const float* b2 = (const float*)d_in[6];
    const float* w3 = (const float*)d_in[7];
    const float* b3 = (const float*)d_in[8];
    float* out = (float*)d_out;

    char* ws = (char*)d_ws;
    float4*    pointsT = (float4*)ws;                    // 131072 B
    float4*    knnT    = (float4*)(ws + 131072);         // 131072 B
    _Float16*  featH   = (_Float16*)(ws + 262144);       // 1048576 B
    int*       idx_ws  = (int*)(ws + 1310720);           // 1048576 B
    _Float16*  w1h     = (_Float16*)(ws + 2359296);      // 24576 B
    _Float16*  w2h     = (_Float16*)(ws + 2383872);      // 16384 B
    _Float16*  w3h     = (_Float16*)(ws + 2400256);      // 8192 B
    float*     lossbuf = (float*)(ws + 2408448);         // 32768 B

    setup_kernel<<<248, 256, 0, stream>>>(points, knn, feat, w1, w2, w3,
                                          pointsT, knnT, featH, w1h, w2h, w3h,
                                          lossbuf);
    scan_kernel<<<1024, 256, 0, stream>>>(pointsT, knnT, idx_ws, lossbuf);
    mlp_kernel<<<(BB * NN) / 2, 256, 0, stream>>>(pointsT, knnT, featH, idx_ws,
                                                  w1h, b1, w2h, b2, w3h, b3,
                                                  lossbuf, out);
}